// Round 1
// baseline (3263.869 us; speedup 1.0000x reference)
//
#include <hip/hip_runtime.h>

// GCN: 100K nodes, 2.5M edges, dims 4 -> 32 -> (32x32 conv x3) -> 3.
// Formulation: g[n] = dinv[n] * (h @ W)[n];  out[dst] = dinv[dst]*(sum g[src] + g[dst]) + b
// Self-loop term g[n] is the initial value of the accumulator S, so no memset of S needed.

constexpr int N_NODES = 100000;
constexpr int N_EDGES = 2500000;

// ---- degree count: deg[n] = #(dst == n); self-loop +1 added in k_dinv ----
__global__ __launch_bounds__(256) void k_count(const int* __restrict__ ei,
                                               int* __restrict__ deg) {
    int e = blockIdx.x * 256 + threadIdx.x;
    if (e < N_EDGES) {
        int d = ei[N_EDGES + e];
        if ((unsigned)d < (unsigned)N_NODES) atomicAdd(&deg[d], 1);
    }
}

__global__ __launch_bounds__(256) void k_dinv(const int* __restrict__ deg,
                                              float* __restrict__ dinv) {
    int n = blockIdx.x * 256 + threadIdx.x;
    if (n < N_NODES) dinv[n] = rsqrtf((float)(deg[n] + 1));  // +1 self-loop; always > 0
}

// ---- fused: t = relu(x@Wfc1 + bfc1); g = dinv * (t@Wc1); S = g (self-loop init) ----
__global__ __launch_bounds__(256) void k_fc1_conv1(
        const float* __restrict__ x,
        const float* __restrict__ Wfc1, const float* __restrict__ bfc1,
        const float* __restrict__ Wc1, const float* __restrict__ dinv,
        float* __restrict__ g, float* __restrict__ S) {
    __shared__ float  sWf[128];   // 4x32
    __shared__ float  sbf[32];
    __shared__ float4 sW[256];    // 32x32 as float4 rows
    if (threadIdx.x < 128) sWf[threadIdx.x] = Wfc1[threadIdx.x];
    if (threadIdx.x < 32)  sbf[threadIdx.x] = bfc1[threadIdx.x];
    sW[threadIdx.x] = ((const float4*)Wc1)[threadIdx.x];
    __syncthreads();

    int n = blockIdx.x * 256 + threadIdx.x;
    if (n >= N_NODES) return;

    float4 xin = *(const float4*)(x + (size_t)n * 4);
    float t[32];
#pragma unroll
    for (int j = 0; j < 32; ++j) {
        float a = fmaf(xin.x, sWf[j], sbf[j]);
        a = fmaf(xin.y, sWf[32 + j], a);
        a = fmaf(xin.z, sWf[64 + j], a);
        a = fmaf(xin.w, sWf[96 + j], a);
        t[j] = fmaxf(a, 0.0f);
    }

    float4 o[8];
#pragma unroll
    for (int q = 0; q < 8; ++q) o[q] = make_float4(0.f, 0.f, 0.f, 0.f);
#pragma unroll
    for (int k = 0; k < 32; ++k) {
        float a = t[k];
#pragma unroll
        for (int q = 0; q < 8; ++q) {
            float4 w = sW[k * 8 + q];
            o[q].x = fmaf(a, w.x, o[q].x);
            o[q].y = fmaf(a, w.y, o[q].y);
            o[q].z = fmaf(a, w.z, o[q].z);
            o[q].w = fmaf(a, w.w, o[q].w);
        }
    }

    float dv = dinv[n];
    float4* gp = (float4*)(g + (size_t)n * 32);
    float4* Sp = (float4*)(S + (size_t)n * 32);
#pragma unroll
    for (int q = 0; q < 8; ++q) {
        float4 v = make_float4(dv * o[q].x, dv * o[q].y, dv * o[q].z, dv * o[q].w);
        gp[q] = v;
        Sp[q] = v;
    }
}

// ---- mid layer: t = relu(dinv*S + b_prev); g = dinv*(t@W); S = g (in-place, per-thread rows) ----
__global__ __launch_bounds__(256) void k_mid(
        const float* __restrict__ bprev, const float* __restrict__ W,
        const float* __restrict__ dinv,
        float* __restrict__ g, float* __restrict__ S) {
    __shared__ float  sb[32];
    __shared__ float4 sW[256];
    if (threadIdx.x < 32) sb[threadIdx.x] = bprev[threadIdx.x];
    sW[threadIdx.x] = ((const float4*)W)[threadIdx.x];
    __syncthreads();

    int n = blockIdx.x * 256 + threadIdx.x;
    if (n >= N_NODES) return;

    float dv = dinv[n];
    const float4* Sp = (const float4*)(S + (size_t)n * 32);
    float t[32];
#pragma unroll
    for (int q = 0; q < 8; ++q) {
        float4 v = Sp[q];
        t[q * 4 + 0] = fmaxf(fmaf(dv, v.x, sb[q * 4 + 0]), 0.0f);
        t[q * 4 + 1] = fmaxf(fmaf(dv, v.y, sb[q * 4 + 1]), 0.0f);
        t[q * 4 + 2] = fmaxf(fmaf(dv, v.z, sb[q * 4 + 2]), 0.0f);
        t[q * 4 + 3] = fmaxf(fmaf(dv, v.w, sb[q * 4 + 3]), 0.0f);
    }

    float4 o[8];
#pragma unroll
    for (int q = 0; q < 8; ++q) o[q] = make_float4(0.f, 0.f, 0.f, 0.f);
#pragma unroll
    for (int k = 0; k < 32; ++k) {
        float a = t[k];
#pragma unroll
        for (int q = 0; q < 8; ++q) {
            float4 w = sW[k * 8 + q];
            o[q].x = fmaf(a, w.x, o[q].x);
            o[q].y = fmaf(a, w.y, o[q].y);
            o[q].z = fmaf(a, w.z, o[q].z);
            o[q].w = fmaf(a, w.w, o[q].w);
        }
    }

    float4* gp = (float4*)(g + (size_t)n * 32);
    float4* Swp = (float4*)(S + (size_t)n * 32);
#pragma unroll
    for (int q = 0; q < 8; ++q) {
        float4 v = make_float4(dv * o[q].x, dv * o[q].y, dv * o[q].z, dv * o[q].w);
        gp[q] = v;
        Swp[q] = v;
    }
}

// ---- edge scatter: S[dst] += g[src].  8 threads/edge, float4 each, 4 fp32 atomics ----
__global__ __launch_bounds__(256) void k_scatter(const int* __restrict__ ei,
                                                 const float* __restrict__ g,
                                                 float* __restrict__ S) {
    int tid = blockIdx.x * 256 + threadIdx.x;
    int e = tid >> 3;
    if (e >= N_EDGES) return;
    int sub = tid & 7;
    int src = ei[e];
    int dst = ei[N_EDGES + e];
    if ((unsigned)src >= (unsigned)N_NODES || (unsigned)dst >= (unsigned)N_NODES) return;
    float4 v = *(const float4*)(g + (size_t)src * 32 + sub * 4);
    float* o = S + (size_t)dst * 32 + sub * 4;
    unsafeAtomicAdd(o + 0, v.x);
    unsafeAtomicAdd(o + 1, v.y);
    unsafeAtomicAdd(o + 2, v.z);
    unsafeAtomicAdd(o + 3, v.w);
}

// ---- output: t = relu(dinv*S + bc3); out = t@Wfc2 + bfc2 ----
__global__ __launch_bounds__(256) void k_out(
        const float* __restrict__ bc3, const float* __restrict__ Wfc2,
        const float* __restrict__ bfc2, const float* __restrict__ dinv,
        const float* __restrict__ S, float* __restrict__ out) {
    __shared__ float sb[32];
    __shared__ float sW[96];   // 32x3
    __shared__ float sb2[3];
    if (threadIdx.x < 32) sb[threadIdx.x] = bc3[threadIdx.x];
    if (threadIdx.x < 96) sW[threadIdx.x] = Wfc2[threadIdx.x];
    if (threadIdx.x < 3)  sb2[threadIdx.x] = bfc2[threadIdx.x];
    __syncthreads();

    int n = blockIdx.x * 256 + threadIdx.x;
    if (n >= N_NODES) return;

    float dv = dinv[n];
    const float4* Sp = (const float4*)(S + (size_t)n * 32);
    float t[32];
#pragma unroll
    for (int q = 0; q < 8; ++q) {
        float4 v = Sp[q];
        t[q * 4 + 0] = fmaxf(fmaf(dv, v.x, sb[q * 4 + 0]), 0.0f);
        t[q * 4 + 1] = fmaxf(fmaf(dv, v.y, sb[q * 4 + 1]), 0.0f);
        t[q * 4 + 2] = fmaxf(fmaf(dv, v.z, sb[q * 4 + 2]), 0.0f);
        t[q * 4 + 3] = fmaxf(fmaf(dv, v.w, sb[q * 4 + 3]), 0.0f);
    }

    float o0 = sb2[0], o1 = sb2[1], o2 = sb2[2];
#pragma unroll
    for (int k = 0; k < 32; ++k) {
        o0 = fmaf(t[k], sW[k * 3 + 0], o0);
        o1 = fmaf(t[k], sW[k * 3 + 1], o1);
        o2 = fmaf(t[k], sW[k * 3 + 2], o2);
    }
    out[(size_t)n * 3 + 0] = o0;
    out[(size_t)n * 3 + 1] = o1;
    out[(size_t)n * 3 + 2] = o2;
}

extern "C" void kernel_launch(void* const* d_in, const int* in_sizes, int n_in,
                              void* d_out, int out_size, void* d_ws, size_t ws_size,
                              hipStream_t stream) {
    const float* x    = (const float*)d_in[0];
    const int*   ei   = (const int*)d_in[1];     // [2, E] int32
    const float* Wfc1 = (const float*)d_in[2];
    const float* bfc1 = (const float*)d_in[3];
    const float* Wc1  = (const float*)d_in[4];
    const float* bc1  = (const float*)d_in[5];
    const float* Wc2  = (const float*)d_in[6];
    const float* bc2  = (const float*)d_in[7];
    const float* Wc3  = (const float*)d_in[8];
    const float* bc3  = (const float*)d_in[9];
    const float* Wfc2 = (const float*)d_in[10];
    const float* bfc2 = (const float*)d_in[11];
    float* out = (float*)d_out;

    char* ws = (char*)d_ws;
    const size_t feat_bytes = (size_t)N_NODES * 32 * sizeof(float);   // 12.8 MB
    float* S    = (float*)ws;
    float* g    = (float*)(ws + feat_bytes);
    float* dinv = (float*)(ws + 2 * feat_bytes);
    int*   deg  = (int*)  (ws + 2 * feat_bytes + (size_t)N_NODES * sizeof(float));

    const int nb_n = (N_NODES + 255) / 256;           // 391
    const int nb_e = (N_EDGES + 255) / 256;           // 9766
    const int nb_s = (N_EDGES * 8 + 255) / 256;       // 78125

    hipMemsetAsync(deg, 0, (size_t)N_NODES * sizeof(int), stream);
    k_count<<<nb_e, 256, 0, stream>>>(ei, deg);
    k_dinv<<<nb_n, 256, 0, stream>>>(deg, dinv);
    k_fc1_conv1<<<nb_n, 256, 0, stream>>>(x, Wfc1, bfc1, Wc1, dinv, g, S);
    k_scatter<<<nb_s, 256, 0, stream>>>(ei, g, S);
    k_mid<<<nb_n, 256, 0, stream>>>(bc1, Wc2, dinv, g, S);
    k_scatter<<<nb_s, 256, 0, stream>>>(ei, g, S);
    k_mid<<<nb_n, 256, 0, stream>>>(bc2, Wc3, dinv, g, S);
    k_scatter<<<nb_s, 256, 0, stream>>>(ei, g, S);
    k_out<<<nb_n, 256, 0, stream>>>(bc3, Wfc2, bfc2, dinv, S, out);
}

// Round 2
// 622.435 us; speedup vs baseline: 5.2437x; 5.2437x over previous
//
#include <hip/hip_runtime.h>

// GCN: 100K nodes, 2.5M edges, dims 4 -> 32 -> (32x32 conv x3) -> 3.
// Round 2: replace fp32-atomic edge scatter (3x1007us, 80M memory-side atomics each)
// with per-launch CSR build + atomic-free gather.
// Formulation: g[n] = dinv[n] * (h @ W)[n];  S[n] = g[n] + sum_{e: dst=n} g[src[e]]
// then next layer input t = relu(dinv*S + b).

constexpr int N_NODES = 100000;
constexpr int N_EDGES = 2500000;
constexpr int NB = (N_NODES + 255) / 256;   // 391 blocks over nodes

// ---- degree count: deg[n] = #(dst == n) ----
__global__ __launch_bounds__(256) void k_count(const int* __restrict__ ei,
                                               int* __restrict__ deg) {
    int e = blockIdx.x * 256 + threadIdx.x;
    if (e < N_EDGES) {
        int d = ei[N_EDGES + e];
        if ((unsigned)d < (unsigned)N_NODES) atomicAdd(&deg[d], 1);
    }
}

__global__ __launch_bounds__(256) void k_dinv(const int* __restrict__ deg,
                                              float* __restrict__ dinv) {
    int n = blockIdx.x * 256 + threadIdx.x;
    if (n < N_NODES) dinv[n] = rsqrtf((float)(deg[n] + 1));  // +1 self-loop; always > 0
}

// ---- scan stage 1: per-block sums of deg ----
__global__ __launch_bounds__(256) void k_blksum(const int* __restrict__ deg,
                                                int* __restrict__ blksum) {
    __shared__ int red[256];
    int tid = threadIdx.x;
    int n = blockIdx.x * 256 + tid;
    red[tid] = (n < N_NODES) ? deg[n] : 0;
    __syncthreads();
#pragma unroll
    for (int s = 128; s > 0; s >>= 1) {
        if (tid < s) red[tid] += red[tid + s];
        __syncthreads();
    }
    if (tid == 0) blksum[blockIdx.x] = red[0];
}

// ---- scan stage 2: single-block exclusive scan of 391 block sums ----
__global__ __launch_bounds__(512) void k_blkscan(const int* __restrict__ blksum,
                                                 int* __restrict__ blkoff) {
    __shared__ int sc[512];
    int tid = threadIdx.x;
    int v = (tid < NB) ? blksum[tid] : 0;
    sc[tid] = v;
    __syncthreads();
#pragma unroll
    for (int off = 1; off < 512; off <<= 1) {
        int t = (tid >= off) ? sc[tid - off] : 0;
        __syncthreads();
        sc[tid] += t;
        __syncthreads();
    }
    if (tid < NB) blkoff[tid] = sc[tid] - v;   // exclusive
}

// ---- scan stage 3: intra-block exclusive scan -> rowptr, cursor ----
__global__ __launch_bounds__(256) void k_rowptr(const int* __restrict__ deg,
                                                const int* __restrict__ blkoff,
                                                int* __restrict__ rowptr,
                                                int* __restrict__ cursor) {
    __shared__ int sc[256];
    int tid = threadIdx.x;
    int n = blockIdx.x * 256 + tid;
    int v = (n < N_NODES) ? deg[n] : 0;
    sc[tid] = v;
    __syncthreads();
#pragma unroll
    for (int off = 1; off < 256; off <<= 1) {
        int t = (tid >= off) ? sc[tid - off] : 0;
        __syncthreads();
        sc[tid] += t;
        __syncthreads();
    }
    int excl = sc[tid] - v + blkoff[blockIdx.x];
    if (n < N_NODES) {
        rowptr[n] = excl;
        cursor[n] = excl;
        if (n == N_NODES - 1) rowptr[N_NODES] = excl + v;
    }
}

// ---- fill CSR: csr_src grouped by dst ----
__global__ __launch_bounds__(256) void k_fill(const int* __restrict__ ei,
                                              int* __restrict__ cursor,
                                              int* __restrict__ csr_src) {
    int e = blockIdx.x * 256 + threadIdx.x;
    if (e >= N_EDGES) return;
    int s = ei[e];
    int d = ei[N_EDGES + e];
    if ((unsigned)s >= (unsigned)N_NODES || (unsigned)d >= (unsigned)N_NODES) return;
    int pos = atomicAdd(&cursor[d], 1);
    csr_src[pos] = s;
}

// ---- fused: t = relu(x@Wfc1 + bfc1); g = dinv * (t@Wc1) ----
__global__ __launch_bounds__(256) void k_fc1_conv1(
        const float* __restrict__ x,
        const float* __restrict__ Wfc1, const float* __restrict__ bfc1,
        const float* __restrict__ Wc1, const float* __restrict__ dinv,
        float* __restrict__ g) {
    __shared__ float  sWf[128];   // 4x32
    __shared__ float  sbf[32];
    __shared__ float4 sW[256];    // 32x32 as float4 rows
    if (threadIdx.x < 128) sWf[threadIdx.x] = Wfc1[threadIdx.x];
    if (threadIdx.x < 32)  sbf[threadIdx.x] = bfc1[threadIdx.x];
    sW[threadIdx.x] = ((const float4*)Wc1)[threadIdx.x];
    __syncthreads();

    int n = blockIdx.x * 256 + threadIdx.x;
    if (n >= N_NODES) return;

    float4 xin = *(const float4*)(x + (size_t)n * 4);
    float t[32];
#pragma unroll
    for (int j = 0; j < 32; ++j) {
        float a = fmaf(xin.x, sWf[j], sbf[j]);
        a = fmaf(xin.y, sWf[32 + j], a);
        a = fmaf(xin.z, sWf[64 + j], a);
        a = fmaf(xin.w, sWf[96 + j], a);
        t[j] = fmaxf(a, 0.0f);
    }

    float4 o[8];
#pragma unroll
    for (int q = 0; q < 8; ++q) o[q] = make_float4(0.f, 0.f, 0.f, 0.f);
#pragma unroll
    for (int k = 0; k < 32; ++k) {
        float a = t[k];
#pragma unroll
        for (int q = 0; q < 8; ++q) {
            float4 w = sW[k * 8 + q];
            o[q].x = fmaf(a, w.x, o[q].x);
            o[q].y = fmaf(a, w.y, o[q].y);
            o[q].z = fmaf(a, w.z, o[q].z);
            o[q].w = fmaf(a, w.w, o[q].w);
        }
    }

    float dv = dinv[n];
    float4* gp = (float4*)(g + (size_t)n * 32);
#pragma unroll
    for (int q = 0; q < 8; ++q)
        gp[q] = make_float4(dv * o[q].x, dv * o[q].y, dv * o[q].z, dv * o[q].w);
}

// ---- gather: S[n] = g[n] + sum_{k in [rowptr[n],rowptr[n+1])} g[csr_src[k]] ----
// 8 threads per node; each thread owns a float4 slice; octet read = 128B coalesced.
__global__ __launch_bounds__(256) void k_gather(const int* __restrict__ rowptr,
                                                const int* __restrict__ csr_src,
                                                const float* __restrict__ g,
                                                float* __restrict__ S) {
    int tid = blockIdx.x * 256 + threadIdx.x;
    int n = tid >> 3;
    if (n >= N_NODES) return;
    int sub = (tid & 7) * 4;
    int beg = rowptr[n];
    int end = rowptr[n + 1];
    float4 acc = *(const float4*)(g + (size_t)n * 32 + sub);   // self-loop term
    for (int k = beg; k < end; ++k) {
        int s = csr_src[k];
        float4 v = *(const float4*)(g + (size_t)s * 32 + sub);
        acc.x += v.x; acc.y += v.y; acc.z += v.z; acc.w += v.w;
    }
    *(float4*)(S + (size_t)n * 32 + sub) = acc;
}

// ---- mid layer: t = relu(dinv*S + b_prev); g = dinv*(t@W) ----
__global__ __launch_bounds__(256) void k_mid(
        const float* __restrict__ bprev, const float* __restrict__ W,
        const float* __restrict__ dinv,
        const float* __restrict__ S, float* __restrict__ g) {
    __shared__ float  sb[32];
    __shared__ float4 sW[256];
    if (threadIdx.x < 32) sb[threadIdx.x] = bprev[threadIdx.x];
    sW[threadIdx.x] = ((const float4*)W)[threadIdx.x];
    __syncthreads();

    int n = blockIdx.x * 256 + threadIdx.x;
    if (n >= N_NODES) return;

    float dv = dinv[n];
    const float4* Sp = (const float4*)(S + (size_t)n * 32);
    float t[32];
#pragma unroll
    for (int q = 0; q < 8; ++q) {
        float4 v = Sp[q];
        t[q * 4 + 0] = fmaxf(fmaf(dv, v.x, sb[q * 4 + 0]), 0.0f);
        t[q * 4 + 1] = fmaxf(fmaf(dv, v.y, sb[q * 4 + 1]), 0.0f);
        t[q * 4 + 2] = fmaxf(fmaf(dv, v.z, sb[q * 4 + 2]), 0.0f);
        t[q * 4 + 3] = fmaxf(fmaf(dv, v.w, sb[q * 4 + 3]), 0.0f);
    }

    float4 o[8];
#pragma unroll
    for (int q = 0; q < 8; ++q) o[q] = make_float4(0.f, 0.f, 0.f, 0.f);
#pragma unroll
    for (int k = 0; k < 32; ++k) {
        float a = t[k];
#pragma unroll
        for (int q = 0; q < 8; ++q) {
            float4 w = sW[k * 8 + q];
            o[q].x = fmaf(a, w.x, o[q].x);
            o[q].y = fmaf(a, w.y, o[q].y);
            o[q].z = fmaf(a, w.z, o[q].z);
            o[q].w = fmaf(a, w.w, o[q].w);
        }
    }

    float4* gp = (float4*)(g + (size_t)n * 32);
#pragma unroll
    for (int q = 0; q < 8; ++q)
        gp[q] = make_float4(dv * o[q].x, dv * o[q].y, dv * o[q].z, dv * o[q].w);
}

// ---- output: t = relu(dinv*S + bc3); out = t@Wfc2 + bfc2 ----
__global__ __launch_bounds__(256) void k_out(
        const float* __restrict__ bc3, const float* __restrict__ Wfc2,
        const float* __restrict__ bfc2, const float* __restrict__ dinv,
        const float* __restrict__ S, float* __restrict__ out) {
    __shared__ float sb[32];
    __shared__ float sW[96];   // 32x3
    __shared__ float sb2[3];
    if (threadIdx.x < 32) sb[threadIdx.x] = bc3[threadIdx.x];
    if (threadIdx.x < 96) sW[threadIdx.x] = Wfc2[threadIdx.x];
    if (threadIdx.x < 3)  sb2[threadIdx.x] = bfc2[threadIdx.x];
    __syncthreads();

    int n = blockIdx.x * 256 + threadIdx.x;
    if (n >= N_NODES) return;

    float dv = dinv[n];
    const float4* Sp = (const float4*)(S + (size_t)n * 32);
    float t[32];
#pragma unroll
    for (int q = 0; q < 8; ++q) {
        float4 v = Sp[q];
        t[q * 4 + 0] = fmaxf(fmaf(dv, v.x, sb[q * 4 + 0]), 0.0f);
        t[q * 4 + 1] = fmaxf(fmaf(dv, v.y, sb[q * 4 + 1]), 0.0f);
        t[q * 4 + 2] = fmaxf(fmaf(dv, v.z, sb[q * 4 + 2]), 0.0f);
        t[q * 4 + 3] = fmaxf(fmaf(dv, v.w, sb[q * 4 + 3]), 0.0f);
    }

    float o0 = sb2[0], o1 = sb2[1], o2 = sb2[2];
#pragma unroll
    for (int k = 0; k < 32; ++k) {
        o0 = fmaf(t[k], sW[k * 3 + 0], o0);
        o1 = fmaf(t[k], sW[k * 3 + 1], o1);
        o2 = fmaf(t[k], sW[k * 3 + 2], o2);
    }
    out[(size_t)n * 3 + 0] = o0;
    out[(size_t)n * 3 + 1] = o1;
    out[(size_t)n * 3 + 2] = o2;
}

extern "C" void kernel_launch(void* const* d_in, const int* in_sizes, int n_in,
                              void* d_out, int out_size, void* d_ws, size_t ws_size,
                              hipStream_t stream) {
    const float* x    = (const float*)d_in[0];
    const int*   ei   = (const int*)d_in[1];     // [2, E] int32
    const float* Wfc1 = (const float*)d_in[2];
    const float* bfc1 = (const float*)d_in[3];
    const float* Wc1  = (const float*)d_in[4];
    const float* bc1  = (const float*)d_in[5];
    const float* Wc2  = (const float*)d_in[6];
    const float* bc2  = (const float*)d_in[7];
    const float* Wc3  = (const float*)d_in[8];
    const float* bc3  = (const float*)d_in[9];
    const float* Wfc2 = (const float*)d_in[10];
    const float* bfc2 = (const float*)d_in[11];
    float* out = (float*)d_out;

    char* ws = (char*)d_ws;
    const size_t feat_bytes = (size_t)N_NODES * 32 * sizeof(float);   // 12.8 MB
    size_t off = 0;
    float* S       = (float*)(ws + off); off += feat_bytes;
    float* g       = (float*)(ws + off); off += feat_bytes;
    int*   csr_src = (int*)  (ws + off); off += (size_t)N_EDGES * sizeof(int);     // 10 MB
    float* dinv    = (float*)(ws + off); off += (size_t)N_NODES * sizeof(float);
    int*   deg     = (int*)  (ws + off); off += (size_t)N_NODES * sizeof(int);
    int*   rowptr  = (int*)  (ws + off); off += (size_t)(N_NODES + 1) * sizeof(int);
    int*   cursor  = (int*)  (ws + off); off += (size_t)N_NODES * sizeof(int);
    int*   blksum  = (int*)  (ws + off); off += (size_t)NB * sizeof(int);
    int*   blkoff  = (int*)  (ws + off); off += (size_t)NB * sizeof(int);

    const int nb_n = NB;                               // 391
    const int nb_e = (N_EDGES + 255) / 256;            // 9766
    const int nb_g = (N_NODES * 8 + 255) / 256;        // 3125

    hipMemsetAsync(deg, 0, (size_t)N_NODES * sizeof(int), stream);
    k_count<<<nb_e, 256, 0, stream>>>(ei, deg);
    k_dinv<<<nb_n, 256, 0, stream>>>(deg, dinv);
    k_blksum<<<nb_n, 256, 0, stream>>>(deg, blksum);
    k_blkscan<<<1, 512, 0, stream>>>(blksum, blkoff);
    k_rowptr<<<nb_n, 256, 0, stream>>>(deg, blkoff, rowptr, cursor);
    k_fill<<<nb_e, 256, 0, stream>>>(ei, cursor, csr_src);

    k_fc1_conv1<<<nb_n, 256, 0, stream>>>(x, Wfc1, bfc1, Wc1, dinv, g);
    k_gather<<<nb_g, 256, 0, stream>>>(rowptr, csr_src, g, S);
    k_mid<<<nb_n, 256, 0, stream>>>(bc1, Wc2, dinv, S, g);
    k_gather<<<nb_g, 256, 0, stream>>>(rowptr, csr_src, g, S);
    k_mid<<<nb_n, 256, 0, stream>>>(bc2, Wc3, dinv, S, g);
    k_gather<<<nb_g, 256, 0, stream>>>(rowptr, csr_src, g, S);
    k_out<<<nb_n, 256, 0, stream>>>(bc3, Wfc2, bfc2, dinv, S, out);
}